// Round 1
// baseline (317.578 us; speedup 1.0000x reference)
//
#include <hip/hip_runtime.h>

typedef unsigned short u16;
typedef __bf16 bf16x8 __attribute__((ext_vector_type(8)));
typedef float f32x4 __attribute__((ext_vector_type(4)));

#define D_MODEL 768
#define NH 12
#define SEQ 2048
#define BB 4

__device__ __forceinline__ u16 f2b(float f) {
  __bf16 h = (__bf16)f;
  return __builtin_bit_cast(u16, h);
}

__device__ __forceinline__ void gload16(const void* g, void* l) {
  __builtin_amdgcn_global_load_lds((__attribute__((address_space(1))) void*)g,
                                   (__attribute__((address_space(3))) void*)l, 16, 0, 0);
}

__device__ __forceinline__ f32x4 mm16(bf16x8 a, bf16x8 b, f32x4 c) {
  return __builtin_amdgcn_mfma_f32_16x16x32_bf16(a, b, c, 0, 0, 0);
}

// ---------------- pack kernels ----------------
__global__ void cast_x_kernel(const float* __restrict__ x, u16* __restrict__ xb) {
  int i = (blockIdx.x * 256 + threadIdx.x) * 4;
  if (i < 8192 * D_MODEL) {
    float4 v = *(const float4*)&x[i];
    ushort4 o;
    o.x = f2b(v.x); o.y = f2b(v.y); o.z = f2b(v.z); o.w = f2b(v.w);
    *(ushort4*)&xb[i] = o;
  }
}

// Wt[c'][d], c' = proj*768 + h*64 + e  (B^T for QKV gemm)
// Wot[d][c], c = h*64 + e             (B^T for out-proj gemm)
__global__ void pack_w_kernel(const float* __restrict__ wq, const float* __restrict__ wk,
                              const float* __restrict__ wv, const float* __restrict__ wo,
                              u16* __restrict__ wt, u16* __restrict__ wot) {
  int i = blockIdx.x * 256 + threadIdx.x;
  if (i < 2304 * 768) {
    int cp = i / 768, d = i % 768;
    int proj = cp / 768, c = cp % 768, h = c / 64, e = c % 64;
    const float* W = (proj == 0) ? wq : ((proj == 1) ? wk : wv);
    wt[i] = f2b(W[(size_t)h * 49152 + d * 64 + e]);
  }
  if (i < 768 * 768) {
    int d = i / 768, c = i % 768;
    wot[i] = f2b(wo[(size_t)c * 768 + d]);
  }
}

// ---------------- GEMM: C[8192 x N] = A[8192 x 768] * Bt[N x 768]^T ----------------
// 128x128 tile, 4 waves (2x2 of 64x64), BK=32, global_load_lds staging.
// LDS layout [g=k-chunk 0..3][row 0..127][16B] -> conflict-free ds_read_b128.
// MODE 0: QKV epilogue (bias, Q*0.125, V transposed). MODE 1: out-proj (fp32 + b_O).
template<int MODE>
__global__ __launch_bounds__(256) void gemm_kernel(
    const u16* __restrict__ A, const u16* __restrict__ Bt,
    const float* __restrict__ bias0, const float* __restrict__ bias1,
    const float* __restrict__ bias2,
    u16* __restrict__ o_q, u16* __restrict__ o_k, u16* __restrict__ o_v,
    float* __restrict__ outf) {
  __shared__ u16 la[4 * 128 * 8];
  __shared__ u16 lb[4 * 128 * 8];
  const int tid = threadIdx.x;
  const int w = tid >> 6, lane = tid & 63;
  const int lg = lane >> 4, cl = lane & 15;
  const int bm = blockIdx.y, bn = blockIdx.x;
  const int wr = w >> 1, wc = w & 1;

  f32x4 vzero = {0.f, 0.f, 0.f, 0.f};
  f32x4 acc[4][4];
#pragma unroll
  for (int mi = 0; mi < 4; mi++)
#pragma unroll
    for (int ni = 0; ni < 4; ni++) acc[mi][ni] = vzero;

  const u16* aB = A + (size_t)bm * 128 * D_MODEL;
  const u16* bB = Bt + (size_t)bn * 128 * D_MODEL;

  for (int kt = 0; kt < D_MODEL / 32; ++kt) {
    const int kof = kt * 32 + w * 8;
    // wave w stages k-chunk g=w, rows 0..63 and 64..127 (1KB per issue, LDS linear)
    gload16(aB + (size_t)(lane)*D_MODEL + kof, &la[(w * 128 + 0) * 8]);
    gload16(aB + (size_t)(64 + lane) * D_MODEL + kof, &la[(w * 128 + 64) * 8]);
    gload16(bB + (size_t)(lane)*D_MODEL + kof, &lb[(w * 128 + 0) * 8]);
    gload16(bB + (size_t)(64 + lane) * D_MODEL + kof, &lb[(w * 128 + 64) * 8]);
    __syncthreads();  // drains vmcnt -> LDS ready

    bf16x8 af[4], bf[4];
#pragma unroll
    for (int mi = 0; mi < 4; mi++)
      af[mi] = *(const bf16x8*)&la[(lg * 128 + wr * 64 + mi * 16 + cl) * 8];
#pragma unroll
    for (int ni = 0; ni < 4; ni++)
      bf[ni] = *(const bf16x8*)&lb[(lg * 128 + wc * 64 + ni * 16 + cl) * 8];
#pragma unroll
    for (int mi = 0; mi < 4; mi++)
#pragma unroll
      for (int ni = 0; ni < 4; ni++)
        acc[mi][ni] = mm16(af[mi], bf[ni], acc[mi][ni]);
    __syncthreads();  // protect LDS reuse
  }

  if (MODE == 0) {
#pragma unroll
    for (int ni = 0; ni < 4; ni++) {
      const int n = bn * 128 + wc * 64 + ni * 16 + cl;  // 0..2303
      const int proj = n / 768, c = n % 768, h = c / 64, e = c % 64;
      const float bz = ((proj == 0) ? bias0 : ((proj == 1) ? bias1 : bias2))[c];
#pragma unroll
      for (int mi = 0; mi < 4; mi++) {
        const int m0 = bm * 128 + wr * 64 + mi * 16 + lg * 4;  // token, mult of 4
        const int b = m0 >> 11, s0 = m0 & 2047;
        if (proj == 2) {
          // V stored transposed: vT[(b*NH+h)*64+e][s]
          ushort4 pk;
          pk.x = f2b(acc[mi][ni][0] + bz);
          pk.y = f2b(acc[mi][ni][1] + bz);
          pk.z = f2b(acc[mi][ni][2] + bz);
          pk.w = f2b(acc[mi][ni][3] + bz);
          *(ushort4*)&o_v[((size_t)(b * NH + h) * 64 + e) * SEQ + s0] = pk;
        } else {
          u16* dst = (proj == 0) ? o_q : o_k;
#pragma unroll
          for (int r = 0; r < 4; r++) {
            float v = acc[mi][ni][r] + bz;
            if (proj == 0) v *= 0.125f;  // fold 1/sqrt(64) into Q
            dst[((size_t)(b * NH + h) * SEQ + (s0 + r)) * 64 + e] = f2b(v);
          }
        }
      }
    }
  } else {
#pragma unroll
    for (int ni = 0; ni < 4; ni++) {
      const int n = bn * 128 + wc * 64 + ni * 16 + cl;  // 0..767
      const float bz = bias0[n];
#pragma unroll
      for (int mi = 0; mi < 4; mi++) {
        const int m0 = bm * 128 + wr * 64 + mi * 16 + lg * 4;
#pragma unroll
        for (int r = 0; r < 4; r++)
          outf[(size_t)(m0 + r) * D_MODEL + n] = acc[mi][ni][r] + bz;
      }
    }
  }
}

// ---------------- flash attention (causal) ----------------
// grid (qt=32, bh=48); 4 waves x 16 q-rows = 64-row Q tile; KBLK=64.
// Q in regs (pre-scaled by 1/8); K and V^T staged to LDS; P via XOR-swizzled LDS.
__global__ __launch_bounds__(256) void attn_kernel(
    const u16* __restrict__ q_ws, const u16* __restrict__ k_ws,
    const u16* __restrict__ vT_ws, u16* __restrict__ z_ws) {
  __shared__ u16 lk[8 * 64 * 8];   // [e-chunk][k-row][16B]
  __shared__ u16 lv[8 * 64 * 8];   // [kk-chunk][e-row][16B]
  __shared__ u16 lp[4 * 16 * 64];  // per-wave P [16 q][64 kk], swizzled
  const int tid = threadIdx.x, w = tid >> 6, lane = tid & 63;
  const int lg = lane >> 4, cl = lane & 15;
  const int qt = blockIdx.x, bh = blockIdx.y;
  const int q0 = qt * 64;
  const u16* qp = q_ws + (size_t)bh * SEQ * 64;
  const u16* kp = k_ws + (size_t)bh * SEQ * 64;
  const u16* vp = vT_ws + (size_t)bh * 64 * SEQ;

  bf16x8 qf[2];
#pragma unroll
  for (int ks = 0; ks < 2; ks++)
    qf[ks] = *(const bf16x8*)&qp[(size_t)(q0 + w * 16 + cl) * 64 + ks * 32 + lg * 8];

  f32x4 vzero = {0.f, 0.f, 0.f, 0.f};
  f32x4 accO[4];
#pragma unroll
  for (int nb = 0; nb < 4; nb++) accO[nb] = vzero;
  float mrun[4], lrun[4];
#pragma unroll
  for (int r = 0; r < 4; r++) { mrun[r] = -INFINITY; lrun[r] = 0.f; }

  for (int kt = 0; kt <= qt; ++kt) {
    const int k0 = kt * 64;
    __syncthreads();  // previous tile fully consumed
#pragma unroll
    for (int c2 = 0; c2 < 2; c2++) {
      const int ch = w + c2 * 4;
      gload16(kp + (size_t)(k0 + lane) * 64 + ch * 8, &lk[ch * 64 * 8]);
      gload16(vp + (size_t)lane * SEQ + k0 + ch * 8, &lv[ch * 64 * 8]);
    }
    __syncthreads();

    // scores S = Q*K^T (Q pre-scaled): D rows = q (lg*4+r), cols = kk (cl)
    f32x4 sa[4];
#pragma unroll
    for (int cb = 0; cb < 4; cb++) sa[cb] = vzero;
#pragma unroll
    for (int ks = 0; ks < 2; ks++) {
#pragma unroll
      for (int cb = 0; cb < 4; cb++) {
        bf16x8 kf = *(const bf16x8*)&lk[((ks * 4 + lg) * 64 + cb * 16 + cl) * 8];
        sa[cb] = mm16(qf[ks], kf, sa[cb]);
      }
    }
    if (kt == qt) {  // diagonal tile: causal mask
#pragma unroll
      for (int cb = 0; cb < 4; cb++)
#pragma unroll
        for (int r = 0; r < 4; r++)
          if (k0 + cb * 16 + cl > q0 + w * 16 + lg * 4 + r) sa[cb][r] = -1e30f;
    }

    float mx[4];
#pragma unroll
    for (int r = 0; r < 4; r++)
      mx[r] = fmaxf(fmaxf(sa[0][r], sa[1][r]), fmaxf(sa[2][r], sa[3][r]));
#pragma unroll
    for (int d = 1; d < 16; d <<= 1)
#pragma unroll
      for (int r = 0; r < 4; r++) mx[r] = fmaxf(mx[r], __shfl_xor(mx[r], d));

    float mnew[4], scl[4], ps[4];
    u16 pb[4][4];
#pragma unroll
    for (int r = 0; r < 4; r++) {
      mnew[r] = fmaxf(mrun[r], mx[r]);
      scl[r] = __expf(mrun[r] - mnew[r]);  // exp(-inf)=0 on first tile
      ps[r] = 0.f;
    }
#pragma unroll
    for (int cb = 0; cb < 4; cb++)
#pragma unroll
      for (int r = 0; r < 4; r++) {
        float p = __expf(sa[cb][r] - mnew[r]);
        ps[r] += p;
        pb[cb][r] = f2b(p);
      }
#pragma unroll
    for (int d = 1; d < 16; d <<= 1)
#pragma unroll
      for (int r = 0; r < 4; r++) ps[r] += __shfl_xor(ps[r], d);
#pragma unroll
    for (int r = 0; r < 4; r++) {
      lrun[r] = lrun[r] * scl[r] + ps[r];
      mrun[r] = mnew[r];
    }
#pragma unroll
    for (int nb = 0; nb < 4; nb++) {
      accO[nb][0] *= scl[0]; accO[nb][1] *= scl[1];
      accO[nb][2] *= scl[2]; accO[nb][3] *= scl[3];
    }

    // P (D-layout) -> swizzled LDS -> A-fragment layout
#pragma unroll
    for (int cb = 0; cb < 4; cb++)
#pragma unroll
      for (int r = 0; r < 4; r++) {
        const int row = lg * 4 + r, col = cb * 16 + cl;
        const int byt = row * 128 + ((col * 2) ^ ((row & 7) << 4));
        lp[w * 1024 + byt / 2] = pb[cb][r];
      }
#pragma unroll
    for (int kps = 0; kps < 2; kps++) {
      const int byt = cl * 128 + ((kps * 64 + lg * 16) ^ ((cl & 7) << 4));
      bf16x8 pf = *(const bf16x8*)&lp[w * 1024 + byt / 2];
#pragma unroll
      for (int nb = 0; nb < 4; nb++) {
        bf16x8 vf = *(const bf16x8*)&lv[((kps * 4 + lg) * 64 + nb * 16 + cl) * 8];
        accO[nb] = mm16(pf, vf, accO[nb]);
      }
    }
  }

  const int b = bh / NH, h = bh % NH;
#pragma unroll
  for (int nb = 0; nb < 4; nb++)
#pragma unroll
    for (int r = 0; r < 4; r++) {
      const int qrow = q0 + w * 16 + lg * 4 + r;
      const float ov = accO[nb][r] / lrun[r];
      z_ws[((size_t)b * SEQ + qrow) * D_MODEL + h * 64 + nb * 16 + cl] = f2b(ov);
    }
}

// ---------------- launch ----------------
extern "C" void kernel_launch(void* const* d_in, const int* in_sizes, int n_in,
                              void* d_out, int out_size, void* d_ws, size_t ws_size,
                              hipStream_t stream) {
  const float* x = (const float*)d_in[0];
  const float* wq = (const float*)d_in[1];
  const float* bq = (const float*)d_in[2];
  const float* wk = (const float*)d_in[3];
  const float* bk = (const float*)d_in[4];
  const float* wv = (const float*)d_in[5];
  const float* bv = (const float*)d_in[6];
  const float* wo = (const float*)d_in[7];
  const float* bo = (const float*)d_in[8];
  float* out = (float*)d_out;

  char* ws = (char*)d_ws;
  size_t off = 0;
  auto carve = [&](size_t bytes) -> u16* {
    u16* p = (u16*)(ws + off);
    off += (bytes + 255) & ~(size_t)255;
    return p;
  };
  u16* xb = carve((size_t)8192 * 768 * 2);
  u16* wt = carve((size_t)2304 * 768 * 2);
  u16* wot = carve((size_t)768 * 768 * 2);
  u16* qw = carve((size_t)BB * NH * SEQ * 64 * 2);
  u16* kw = carve((size_t)BB * NH * SEQ * 64 * 2);
  u16* vw = carve((size_t)BB * NH * SEQ * 64 * 2);
  u16* zw = carve((size_t)8192 * 768 * 2);
  if (ws_size < off) return;  // workspace too small: fail loudly (wrong output)

  cast_x_kernel<<<dim3(6144), dim3(256), 0, stream>>>(x, xb);
  pack_w_kernel<<<dim3(6912), dim3(256), 0, stream>>>(wq, wk, wv, wo, wt, wot);
  gemm_kernel<0><<<dim3(18, 64), dim3(256), 0, stream>>>(
      xb, wt, bq, bk, bv, qw, kw, vw, nullptr);
  attn_kernel<<<dim3(32, 48), dim3(256), 0, stream>>>(qw, kw, vw, zw);
  gemm_kernel<1><<<dim3(6, 64), dim3(256), 0, stream>>>(
      zw, wot, bo, nullptr, nullptr, nullptr, nullptr, nullptr, out);
}

// Round 2
// 216.851 us; speedup vs baseline: 1.4645x; 1.4645x over previous
//
#include <hip/hip_runtime.h>

typedef unsigned short u16;
typedef __bf16 bf16x8 __attribute__((ext_vector_type(8)));
typedef float f32x4 __attribute__((ext_vector_type(4)));

#define D_MODEL 768
#define NH 12
#define SEQ 2048
#define BB 4

__device__ __forceinline__ u16 f2b(float f) {
  __bf16 h = (__bf16)f;
  return __builtin_bit_cast(u16, h);
}

__device__ __forceinline__ void gload16(const void* g, void* l) {
  __builtin_amdgcn_global_load_lds((__attribute__((address_space(1))) void*)g,
                                   (__attribute__((address_space(3))) void*)l, 16, 0, 0);
}

__device__ __forceinline__ f32x4 mm16(bf16x8 a, bf16x8 b, f32x4 c) {
  return __builtin_amdgcn_mfma_f32_16x16x32_bf16(a, b, c, 0, 0, 0);
}

// ---------------- pack kernels ----------------
__global__ void cast_x_kernel(const float* __restrict__ x, u16* __restrict__ xb) {
  int i = (blockIdx.x * 256 + threadIdx.x) * 4;
  if (i < 8192 * D_MODEL) {
    float4 v = *(const float4*)&x[i];
    ushort4 o;
    o.x = f2b(v.x); o.y = f2b(v.y); o.z = f2b(v.z); o.w = f2b(v.w);
    *(ushort4*)&xb[i] = o;
  }
}

// Wt[c'][d], c' = proj*768 + h*64 + e  (B^T for QKV gemm)
// Wot[d][c], c = h*64 + e             (B^T for out-proj gemm)
__global__ void pack_w_kernel(const float* __restrict__ wq, const float* __restrict__ wk,
                              const float* __restrict__ wv, const float* __restrict__ wo,
                              u16* __restrict__ wt, u16* __restrict__ wot) {
  int i = blockIdx.x * 256 + threadIdx.x;
  if (i < 2304 * 768) {
    int cp = i / 768, d = i % 768;
    int proj = cp / 768, c = cp % 768, h = c / 64, e = c % 64;
    const float* W = (proj == 0) ? wq : ((proj == 1) ? wk : wv);
    wt[i] = f2b(W[(size_t)h * 49152 + d * 64 + e]);
  }
  if (i < 768 * 768) {
    int d = i / 768, c = i % 768;
    wot[i] = f2b(wo[(size_t)c * 768 + d]);
  }
}

// ---------------- GEMM: C[8192 x N] = A[8192 x 768] * Bt[N x 768]^T ----------------
template<int MODE>
__global__ __launch_bounds__(256) void gemm_kernel(
    const u16* __restrict__ A, const u16* __restrict__ Bt,
    const float* __restrict__ bias0, const float* __restrict__ bias1,
    const float* __restrict__ bias2,
    u16* __restrict__ o_q, u16* __restrict__ o_k, u16* __restrict__ o_v,
    float* __restrict__ outf) {
  __shared__ u16 la[4 * 128 * 8];
  __shared__ u16 lb[4 * 128 * 8];
  const int tid = threadIdx.x;
  const int w = tid >> 6, lane = tid & 63;
  const int lg = lane >> 4, cl = lane & 15;
  const int bm = blockIdx.y, bn = blockIdx.x;
  const int wr = w >> 1, wc = w & 1;

  f32x4 vzero = {0.f, 0.f, 0.f, 0.f};
  f32x4 acc[4][4];
#pragma unroll
  for (int mi = 0; mi < 4; mi++)
#pragma unroll
    for (int ni = 0; ni < 4; ni++) acc[mi][ni] = vzero;

  const u16* aB = A + (size_t)bm * 128 * D_MODEL;
  const u16* bB = Bt + (size_t)bn * 128 * D_MODEL;

  for (int kt = 0; kt < D_MODEL / 32; ++kt) {
    const int kof = kt * 32 + w * 8;
    gload16(aB + (size_t)(lane)*D_MODEL + kof, &la[(w * 128 + 0) * 8]);
    gload16(aB + (size_t)(64 + lane) * D_MODEL + kof, &la[(w * 128 + 64) * 8]);
    gload16(bB + (size_t)(lane)*D_MODEL + kof, &lb[(w * 128 + 0) * 8]);
    gload16(bB + (size_t)(64 + lane) * D_MODEL + kof, &lb[(w * 128 + 64) * 8]);
    __syncthreads();

    bf16x8 af[4], bf[4];
#pragma unroll
    for (int mi = 0; mi < 4; mi++)
      af[mi] = *(const bf16x8*)&la[(lg * 128 + wr * 64 + mi * 16 + cl) * 8];
#pragma unroll
    for (int ni = 0; ni < 4; ni++)
      bf[ni] = *(const bf16x8*)&lb[(lg * 128 + wc * 64 + ni * 16 + cl) * 8];
#pragma unroll
    for (int mi = 0; mi < 4; mi++)
#pragma unroll
      for (int ni = 0; ni < 4; ni++)
        acc[mi][ni] = mm16(af[mi], bf[ni], acc[mi][ni]);
    __syncthreads();
  }

  if (MODE == 0) {
#pragma unroll
    for (int ni = 0; ni < 4; ni++) {
      const int n = bn * 128 + wc * 64 + ni * 16 + cl;  // 0..2303
      const int proj = n / 768, c = n % 768, h = c / 64, e = c % 64;
      const float bz = ((proj == 0) ? bias0 : ((proj == 1) ? bias1 : bias2))[c];
#pragma unroll
      for (int mi = 0; mi < 4; mi++) {
        const int m0 = bm * 128 + wr * 64 + mi * 16 + lg * 4;
        const int b = m0 >> 11, s0 = m0 & 2047;
        if (proj == 2) {
          ushort4 pk;
          pk.x = f2b(acc[mi][ni][0] + bz);
          pk.y = f2b(acc[mi][ni][1] + bz);
          pk.z = f2b(acc[mi][ni][2] + bz);
          pk.w = f2b(acc[mi][ni][3] + bz);
          *(ushort4*)&o_v[((size_t)(b * NH + h) * 64 + e) * SEQ + s0] = pk;
        } else {
          u16* dst = (proj == 0) ? o_q : o_k;
#pragma unroll
          for (int r = 0; r < 4; r++) {
            float v = acc[mi][ni][r] + bz;
            if (proj == 0) v *= 0.125f;
            dst[((size_t)(b * NH + h) * SEQ + (s0 + r)) * 64 + e] = f2b(v);
          }
        }
      }
    }
  } else {
#pragma unroll
    for (int ni = 0; ni < 4; ni++) {
      const int n = bn * 128 + wc * 64 + ni * 16 + cl;  // 0..767
      const float bz = bias0[n];
#pragma unroll
      for (int mi = 0; mi < 4; mi++) {
        const int m0 = bm * 128 + wr * 64 + mi * 16 + lg * 4;
#pragma unroll
        for (int r = 0; r < 4; r++)
          outf[(size_t)(m0 + r) * D_MODEL + n] = acc[mi][ni][r] + bz;
      }
    }
  }
}

// ---------------- flash attention (causal, pair-balanced, double-buffered) --------
// grid (pair=16, bh=48). Block handles q-tiles {p, 31-p} -> exactly 33 k-tiles each.
// K/V double-buffered in LDS; prefetch tile kt+1 overlaps compute of tile kt;
// raw s_barrier + explicit vmcnt(0) (one barrier per tile, no early drain).
__global__ __launch_bounds__(256) void attn_kernel(
    const u16* __restrict__ q_ws, const u16* __restrict__ k_ws,
    const u16* __restrict__ vT_ws, u16* __restrict__ z_ws) {
  __shared__ u16 lk[2][8 * 64 * 8];  // [buf][e-chunk][k-row][16B]
  __shared__ u16 lv[2][8 * 64 * 8];  // [buf][kk-chunk][e-row][16B]
  __shared__ u16 lp[4 * 16 * 64];    // per-wave P [16 q][64 kk], swizzled
  const int tid = threadIdx.x, w = tid >> 6, lane = tid & 63;
  const int lg = lane >> 4, cl = lane & 15;
  const int bh = blockIdx.y;
  const u16* qp = q_ws + (size_t)bh * SEQ * 64;
  const u16* kp = k_ws + (size_t)bh * SEQ * 64;
  const u16* vp = vT_ws + (size_t)bh * 64 * SEQ;
  const int b = bh / NH, h = bh % NH;

  for (int sel = 0; sel < 2; ++sel) {
    const int qt = (sel == 0) ? (int)blockIdx.x : 31 - (int)blockIdx.x;
    const int q0 = qt * 64;

    bf16x8 qf[2];
#pragma unroll
    for (int ks = 0; ks < 2; ks++)
      qf[ks] = *(const bf16x8*)&qp[(size_t)(q0 + w * 16 + cl) * 64 + ks * 32 + lg * 8];

    f32x4 vzero = {0.f, 0.f, 0.f, 0.f};
    f32x4 accO[4];
#pragma unroll
    for (int nb = 0; nb < 4; nb++) accO[nb] = vzero;
    float mrun[4], lrun[4];
#pragma unroll
    for (int r = 0; r < 4; r++) { mrun[r] = -INFINITY; lrun[r] = 0.f; }

    // prologue: stage tile 0 into buf 0
#pragma unroll
    for (int c2 = 0; c2 < 2; c2++) {
      const int ch = w + c2 * 4;
      gload16(kp + (size_t)(lane)*64 + ch * 8, &lk[0][ch * 64 * 8]);
      gload16(vp + (size_t)lane * SEQ + ch * 8, &lv[0][ch * 64 * 8]);
    }
    asm volatile("s_waitcnt vmcnt(0)" ::: "memory");
    __builtin_amdgcn_s_barrier();

    for (int kt = 0; kt <= qt; ++kt) {
      const int cur = kt & 1;
      const int k0 = kt * 64;
      if (kt < qt) {  // prefetch next tile into the other buffer
        const int kn = k0 + 64;
#pragma unroll
        for (int c2 = 0; c2 < 2; c2++) {
          const int ch = w + c2 * 4;
          gload16(kp + (size_t)(kn + lane) * 64 + ch * 8, &lk[cur ^ 1][ch * 64 * 8]);
          gload16(vp + (size_t)lane * SEQ + kn + ch * 8, &lv[cur ^ 1][ch * 64 * 8]);
        }
      }

      // scores S = Q*K^T (Q pre-scaled by 1/8)
      f32x4 sa[4];
#pragma unroll
      for (int cb = 0; cb < 4; cb++) sa[cb] = vzero;
      __builtin_amdgcn_s_setprio(1);
#pragma unroll
      for (int ks = 0; ks < 2; ks++) {
#pragma unroll
        for (int cb = 0; cb < 4; cb++) {
          bf16x8 kf = *(const bf16x8*)&lk[cur][((ks * 4 + lg) * 64 + cb * 16 + cl) * 8];
          sa[cb] = mm16(qf[ks], kf, sa[cb]);
        }
      }
      __builtin_amdgcn_s_setprio(0);
      if (kt == qt) {  // diagonal tile: causal mask
#pragma unroll
        for (int cb = 0; cb < 4; cb++)
#pragma unroll
          for (int r = 0; r < 4; r++)
            if (k0 + cb * 16 + cl > q0 + w * 16 + lg * 4 + r) sa[cb][r] = -1e30f;
      }

      float mx[4];
#pragma unroll
      for (int r = 0; r < 4; r++)
        mx[r] = fmaxf(fmaxf(sa[0][r], sa[1][r]), fmaxf(sa[2][r], sa[3][r]));
#pragma unroll
      for (int d = 1; d < 16; d <<= 1)
#pragma unroll
        for (int r = 0; r < 4; r++) mx[r] = fmaxf(mx[r], __shfl_xor(mx[r], d));

      float mnew[4], scl[4], ps[4];
      u16 pb[4][4];
#pragma unroll
      for (int r = 0; r < 4; r++) {
        mnew[r] = fmaxf(mrun[r], mx[r]);
        scl[r] = __expf(mrun[r] - mnew[r]);
        ps[r] = 0.f;
      }
#pragma unroll
      for (int cb = 0; cb < 4; cb++)
#pragma unroll
        for (int r = 0; r < 4; r++) {
          float p = __expf(sa[cb][r] - mnew[r]);
          ps[r] += p;
          pb[cb][r] = f2b(p);
        }
#pragma unroll
      for (int d = 1; d < 16; d <<= 1)
#pragma unroll
        for (int r = 0; r < 4; r++) ps[r] += __shfl_xor(ps[r], d);
#pragma unroll
      for (int r = 0; r < 4; r++) {
        lrun[r] = lrun[r] * scl[r] + ps[r];
        mrun[r] = mnew[r];
      }
#pragma unroll
      for (int nb = 0; nb < 4; nb++) {
        accO[nb][0] *= scl[0]; accO[nb][1] *= scl[1];
        accO[nb][2] *= scl[2]; accO[nb][3] *= scl[3];
      }

      // P (D-layout) -> swizzled LDS -> A-fragment layout
#pragma unroll
      for (int cb = 0; cb < 4; cb++)
#pragma unroll
        for (int r = 0; r < 4; r++) {
          const int row = lg * 4 + r, col = cb * 16 + cl;
          const int byt = row * 128 + ((col * 2) ^ ((row & 7) << 4));
          lp[w * 1024 + byt / 2] = pb[cb][r];
        }
      __builtin_amdgcn_s_setprio(1);
#pragma unroll
      for (int kps = 0; kps < 2; kps++) {
        const int byt = cl * 128 + ((kps * 64 + lg * 16) ^ ((cl & 7) << 4));
        bf16x8 pf = *(const bf16x8*)&lp[w * 1024 + byt / 2];
#pragma unroll
        for (int nb = 0; nb < 4; nb++) {
          bf16x8 vf = *(const bf16x8*)&lv[cur][((kps * 4 + lg) * 64 + nb * 16 + cl) * 8];
          accO[nb] = mm16(pf, vf, accO[nb]);
        }
      }
      __builtin_amdgcn_s_setprio(0);

      // wait prefetch (kt+1) done + all waves done reading buf[cur]
      asm volatile("s_waitcnt vmcnt(0)" ::: "memory");
      __builtin_amdgcn_s_barrier();
    }

#pragma unroll
    for (int nb = 0; nb < 4; nb++)
#pragma unroll
      for (int r = 0; r < 4; r++) {
        const int qrow = q0 + w * 16 + lg * 4 + r;
        const float ov = accO[nb][r] / lrun[r];
        z_ws[((size_t)b * SEQ + qrow) * D_MODEL + h * 64 + nb * 16 + cl] = f2b(ov);
      }
  }
}

// ---------------- launch ----------------
extern "C" void kernel_launch(void* const* d_in, const int* in_sizes, int n_in,
                              void* d_out, int out_size, void* d_ws, size_t ws_size,
                              hipStream_t stream) {
  const float* x = (const float*)d_in[0];
  const float* wq = (const float*)d_in[1];
  const float* bq = (const float*)d_in[2];
  const float* wk = (const float*)d_in[3];
  const float* bk = (const float*)d_in[4];
  const float* wv = (const float*)d_in[5];
  const float* bv = (const float*)d_in[6];
  const float* wo = (const float*)d_in[7];
  const float* bo = (const float*)d_in[8];
  float* out = (float*)d_out;

  char* ws = (char*)d_ws;
  size_t off = 0;
  auto carve = [&](size_t bytes) -> u16* {
    u16* p = (u16*)(ws + off);
    off += (bytes + 255) & ~(size_t)255;
    return p;
  };
  u16* xb = carve((size_t)8192 * 768 * 2);
  u16* wt = carve((size_t)2304 * 768 * 2);
  u16* wot = carve((size_t)768 * 768 * 2);
  u16* qw = carve((size_t)BB * NH * SEQ * 64 * 2);
  u16* kw = carve((size_t)BB * NH * SEQ * 64 * 2);
  u16* vw = carve((size_t)BB * NH * SEQ * 64 * 2);
  u16* zw = carve((size_t)8192 * 768 * 2);
  if (ws_size < off) return;

  cast_x_kernel<<<dim3(6144), dim3(256), 0, stream>>>(x, xb);
  pack_w_kernel<<<dim3(6912), dim3(256), 0, stream>>>(wq, wk, wv, wo, wt, wot);
  gemm_kernel<0><<<dim3(18, 64), dim3(256), 0, stream>>>(
      xb, wt, bq, bk, bv, qw, kw, vw, nullptr);
  attn_kernel<<<dim3(16, 48), dim3(256), 0, stream>>>(qw, kw, vw, zw);
  gemm_kernel<1><<<dim3(6, 64), dim3(256), 0, stream>>>(
      zw, wot, bo, nullptr, nullptr, nullptr, nullptr, nullptr, out);
}

// Round 3
// 192.891 us; speedup vs baseline: 1.6464x; 1.1242x over previous
//
#include <hip/hip_runtime.h>

typedef unsigned short u16;
typedef __bf16 bf16x8 __attribute__((ext_vector_type(8)));
typedef float f32x4 __attribute__((ext_vector_type(4)));

#define D_MODEL 768
#define NH 12
#define SEQ 2048
#define BB 4
// 1/sqrt(64) * log2(e): softmax runs in exp2 domain
#define QSCALE 0.18033688011112042f

__device__ __forceinline__ u16 f2b(float f) {
  __bf16 h = (__bf16)f;
  return __builtin_bit_cast(u16, h);
}

__device__ __forceinline__ void gload16(const void* g, void* l) {
  __builtin_amdgcn_global_load_lds((__attribute__((address_space(1))) void*)g,
                                   (__attribute__((address_space(3))) void*)l, 16, 0, 0);
}

__device__ __forceinline__ f32x4 mm16(bf16x8 a, bf16x8 b, f32x4 c) {
  return __builtin_amdgcn_mfma_f32_16x16x32_bf16(a, b, c, 0, 0, 0);
}

// ---------------- pack kernels ----------------
__global__ void cast_x_kernel(const float* __restrict__ x, u16* __restrict__ xb) {
  int i = (blockIdx.x * 256 + threadIdx.x) * 4;
  if (i < 8192 * D_MODEL) {
    float4 v = *(const float4*)&x[i];
    ushort4 o;
    o.x = f2b(v.x); o.y = f2b(v.y); o.z = f2b(v.z); o.w = f2b(v.w);
    *(ushort4*)&xb[i] = o;
  }
}

// wt[c'][d],  c' = proj*768 + h*64 + e, proj in {Q,K}   (B^T for QK gemm)
// wvt[e'][d], e' = h*64 + e                             (A for V^T gemm)
// wot[d][c],  c = h*64 + e                              (B^T for out-proj gemm)
__global__ void pack_w_kernel(const float* __restrict__ wq, const float* __restrict__ wk,
                              const float* __restrict__ wv, const float* __restrict__ wo,
                              u16* __restrict__ wt, u16* __restrict__ wvt,
                              u16* __restrict__ wot) {
  int i = blockIdx.x * 256 + threadIdx.x;
  if (i < 1536 * 768) {
    int cp = i / 768, d = i % 768;
    int proj = cp / 768, c = cp % 768, h = c / 64, e = c % 64;
    const float* W = (proj == 0) ? wq : wk;
    wt[i] = f2b(W[(size_t)h * 49152 + d * 64 + e]);
  }
  if (i < 768 * 768) {
    int rp = i / 768, d = i % 768;
    int h = rp / 64, e = rp % 64;
    wvt[i] = f2b(wv[(size_t)h * 49152 + d * 64 + e]);
    wot[i] = f2b(wo[(size_t)d * 768 + rp]);  // wot[d'][c]: here rp=row index d', d=col c
  }
}

// ---------------- GEMM: C[M x N] = A[M x 768] * Bt[N x 768]^T ----------------
// 128x128 tile, 4 waves (2x2 of 64x64), BK=32, global_load_lds staging.
// MODE 0: QK epilogue (bias, Q pre-scaled). MODE 1: out-proj (fp32 + b_O).
// MODE 2: V^T gemm (rows = e' = h*64+e, cols = token); coalesced store along s.
template<int MODE>
__global__ __launch_bounds__(256) void gemm_kernel(
    const u16* __restrict__ A, const u16* __restrict__ Bt,
    const float* __restrict__ bias0, const float* __restrict__ bias1,
    u16* __restrict__ o_q, u16* __restrict__ o_k, float* __restrict__ outf) {
  __shared__ u16 la[4 * 128 * 8];
  __shared__ u16 lb[4 * 128 * 8];
  const int tid = threadIdx.x;
  const int w = tid >> 6, lane = tid & 63;
  const int lg = lane >> 4, cl = lane & 15;
  const int bm = blockIdx.y, bn = blockIdx.x;
  const int wr = w >> 1, wc = w & 1;

  f32x4 vzero = {0.f, 0.f, 0.f, 0.f};
  f32x4 acc[4][4];
#pragma unroll
  for (int mi = 0; mi < 4; mi++)
#pragma unroll
    for (int ni = 0; ni < 4; ni++) acc[mi][ni] = vzero;

  const u16* aB = A + (size_t)bm * 128 * D_MODEL;
  const u16* bB = Bt + (size_t)bn * 128 * D_MODEL;

  for (int kt = 0; kt < D_MODEL / 32; ++kt) {
    const int kof = kt * 32 + w * 8;
    gload16(aB + (size_t)(lane)*D_MODEL + kof, &la[(w * 128 + 0) * 8]);
    gload16(aB + (size_t)(64 + lane) * D_MODEL + kof, &la[(w * 128 + 64) * 8]);
    gload16(bB + (size_t)(lane)*D_MODEL + kof, &lb[(w * 128 + 0) * 8]);
    gload16(bB + (size_t)(64 + lane) * D_MODEL + kof, &lb[(w * 128 + 64) * 8]);
    __syncthreads();

    bf16x8 af[4], bf[4];
#pragma unroll
    for (int mi = 0; mi < 4; mi++)
      af[mi] = *(const bf16x8*)&la[(lg * 128 + wr * 64 + mi * 16 + cl) * 8];
#pragma unroll
    for (int ni = 0; ni < 4; ni++)
      bf[ni] = *(const bf16x8*)&lb[(lg * 128 + wc * 64 + ni * 16 + cl) * 8];
#pragma unroll
    for (int mi = 0; mi < 4; mi++)
#pragma unroll
      for (int ni = 0; ni < 4; ni++)
        acc[mi][ni] = mm16(af[mi], bf[ni], acc[mi][ni]);
    __syncthreads();
  }

  if (MODE == 0) {
#pragma unroll
    for (int ni = 0; ni < 4; ni++) {
      const int n = bn * 128 + wc * 64 + ni * 16 + cl;  // 0..1535
      const int proj = n / 768, c = n % 768, h = c / 64, e = c % 64;
      const float bz = (proj == 0 ? bias0 : bias1)[c];
      u16* dst = (proj == 0) ? o_q : o_k;
#pragma unroll
      for (int mi = 0; mi < 4; mi++) {
        const int m0 = bm * 128 + wr * 64 + mi * 16 + lg * 4;  // token
        const int b = m0 >> 11, s0 = m0 & 2047;
#pragma unroll
        for (int r = 0; r < 4; r++) {
          float v = acc[mi][ni][r] + bz;
          if (proj == 0) v *= QSCALE;
          dst[((size_t)(b * NH + h) * SEQ + (s0 + r)) * 64 + e] = f2b(v);
        }
      }
    }
  } else if (MODE == 1) {
#pragma unroll
    for (int ni = 0; ni < 4; ni++) {
      const int n = bn * 128 + wc * 64 + ni * 16 + cl;  // 0..767
      const float bz = bias0[n];
#pragma unroll
      for (int mi = 0; mi < 4; mi++) {
        const int m0 = bm * 128 + wr * 64 + mi * 16 + lg * 4;
#pragma unroll
        for (int r = 0; r < 4; r++)
          outf[(size_t)(m0 + r) * D_MODEL + n] = acc[mi][ni][r] + bz;
      }
    }
  } else {  // MODE 2: V^T, store o_q[(b*768 + m)*2048 + s0]
#pragma unroll
    for (int ni = 0; ni < 4; ni++) {
      const int n = bn * 128 + wc * 64 + ni * 16 + cl;  // token 0..8191
      const int b = n >> 11, s0 = n & 2047;
#pragma unroll
      for (int mi = 0; mi < 4; mi++) {
        const int m0 = bm * 128 + wr * 64 + mi * 16 + lg * 4;  // e' = h*64+e
#pragma unroll
        for (int r = 0; r < 4; r++) {
          const int m = m0 + r;
          o_q[((size_t)(b * 768 + m) << 11) + s0] = f2b(acc[mi][ni][r] + bias0[m]);
        }
      }
    }
  }
}

// ---------------- flash attention (causal, swapped-QK in-register softmax) --------
// grid (pair=16, bh=48); block does q-tiles {p, 31-p} -> 33 k-tiles each.
// QK^T computed as mfma(K,Q): lane owns one q-row (q=cl) x 16 kk values ->
// row reduce = in-lane tree + 2 shfl_xor. P packed 4-at-a-time (ds_write_b64).
__global__ __launch_bounds__(256) void attn_kernel(
    const u16* __restrict__ q_ws, const u16* __restrict__ k_ws,
    const u16* __restrict__ vT_ws, u16* __restrict__ z_ws) {
  __shared__ u16 lk[2][4096];  // [buf][e-chunk 0..7][k-row 0..63][8 e]
  __shared__ u16 lv[2][4096];  // [buf][kk-chunk 0..7][e-row 0..63][8 kk]
  __shared__ u16 lp[4096];     // per-wave P [16 q][64 kk] bf16, XOR-swizzled
  const int tid = threadIdx.x, w = tid >> 6, lane = tid & 63;
  const int lg = lane >> 4, cl = lane & 15, c7 = cl & 7;
  const int bh = blockIdx.y;
  const u16* qp = q_ws + (size_t)bh * SEQ * 64;
  const u16* kp = k_ws + (size_t)bh * SEQ * 64;
  const u16* vp = vT_ws + (size_t)bh * 64 * SEQ;
  const int b = bh / NH, h = bh % NH;

  for (int sel = 0; sel < 2; ++sel) {
    const int qt = (sel == 0) ? (int)blockIdx.x : 31 - (int)blockIdx.x;
    const int q0 = qt * 64;
    const int qabs = q0 + w * 16 + cl;  // this lane's q-row

    bf16x8 qf[2];
#pragma unroll
    for (int ks = 0; ks < 2; ks++)
      qf[ks] = *(const bf16x8*)&qp[(size_t)(q0 + w * 16 + cl) * 64 + ks * 32 + lg * 8];

    f32x4 vzero = {0.f, 0.f, 0.f, 0.f};
    f32x4 accO[4];
#pragma unroll
    for (int nb = 0; nb < 4; nb++) accO[nb] = vzero;
    float mrun = -INFINITY, lrun = 0.f;

    // prologue: stage tile 0 into buf 0
#pragma unroll
    for (int c2 = 0; c2 < 2; c2++) {
      const int ch = w + c2 * 4;
      gload16(kp + (size_t)(lane)*64 + ch * 8, &lk[0][ch * 64 * 8]);
      gload16(vp + (size_t)lane * SEQ + ch * 8, &lv[0][ch * 64 * 8]);
    }
    asm volatile("s_waitcnt vmcnt(0)" ::: "memory");
    __builtin_amdgcn_s_barrier();

    for (int kt = 0; kt <= qt; ++kt) {
      const int cur = kt & 1;
      const int k0 = kt * 64;
      if (kt < qt) {  // prefetch next tile into the other buffer
        const int kn = k0 + 64;
#pragma unroll
        for (int c2 = 0; c2 < 2; c2++) {
          const int ch = w + c2 * 4;
          gload16(kp + (size_t)(kn + lane) * 64 + ch * 8, &lk[cur ^ 1][ch * 64 * 8]);
          gload16(vp + (size_t)lane * SEQ + kn + ch * 8, &lv[cur ^ 1][ch * 64 * 8]);
        }
      }

      // S^T = K * Q^T: D row = kk (cb*16+lg*4+r), col = q (cl)
      f32x4 sa[4];
#pragma unroll
      for (int cb = 0; cb < 4; cb++) sa[cb] = vzero;
      __builtin_amdgcn_s_setprio(1);
#pragma unroll
      for (int ks = 0; ks < 2; ks++) {
#pragma unroll
        for (int cb = 0; cb < 4; cb++) {
          bf16x8 kf = *(const bf16x8*)&lk[cur][((ks * 4 + lg) * 64 + cb * 16 + cl) * 8];
          sa[cb] = mm16(kf, qf[ks], sa[cb]);
        }
      }
      __builtin_amdgcn_s_setprio(0);
      if (kt == qt) {  // diagonal tile: causal mask (kk > q)
#pragma unroll
        for (int cb = 0; cb < 4; cb++)
#pragma unroll
          for (int r = 0; r < 4; r++)
            if (k0 + cb * 16 + lg * 4 + r > qabs) sa[cb][r] = -1e30f;
      }

      // in-lane max over 16, then reduce across the 4 lanes sharing q-row cl
      float mx = fmaxf(fmaxf(fmaxf(sa[0][0], sa[0][1]), fmaxf(sa[0][2], sa[0][3])),
                       fmaxf(fmaxf(sa[1][0], sa[1][1]), fmaxf(sa[1][2], sa[1][3])));
      mx = fmaxf(mx, fmaxf(fmaxf(fmaxf(sa[2][0], sa[2][1]), fmaxf(sa[2][2], sa[2][3])),
                           fmaxf(fmaxf(sa[3][0], sa[3][1]), fmaxf(sa[3][2], sa[3][3]))));
      mx = fmaxf(mx, __shfl_xor(mx, 16));
      mx = fmaxf(mx, __shfl_xor(mx, 32));

      const float mnew = fmaxf(mrun, mx);
      const float scl = __builtin_amdgcn_exp2f(mrun - mnew);  // exp2(-inf)=0 first tile
      float ps = 0.f;
#pragma unroll
      for (int cb = 0; cb < 4; cb++) {
        float p0 = __builtin_amdgcn_exp2f(sa[cb][0] - mnew);
        float p1 = __builtin_amdgcn_exp2f(sa[cb][1] - mnew);
        float p2 = __builtin_amdgcn_exp2f(sa[cb][2] - mnew);
        float p3 = __builtin_amdgcn_exp2f(sa[cb][3] - mnew);
        ps += (p0 + p1) + (p2 + p3);
        ushort4 pk;
        pk.x = f2b(p0); pk.y = f2b(p1); pk.z = f2b(p2); pk.w = f2b(p3);
        // P[q=cl][kk=cb*16+lg*4 .. +3], swizzled row of 128B
        *(ushort4*)&lp[w * 1024 + (cl * 128 + ((cb * 32 + lg * 8) ^ (c7 << 4))) / 2] = pk;
      }
      ps += __shfl_xor(ps, 16);
      ps += __shfl_xor(ps, 32);
      lrun = lrun * scl + ps;
      mrun = mnew;

      // redistribute scl to the accO row owners (accO row q = lg*4+r)
      f32x4 s4;
#pragma unroll
      for (int r = 0; r < 4; r++) s4[r] = __shfl(scl, lg * 4 + r);
#pragma unroll
      for (int nb = 0; nb < 4; nb++) accO[nb] *= s4;

      // PV: A = P (row q=cl), B = V^T
      __builtin_amdgcn_s_setprio(1);
#pragma unroll
      for (int ks = 0; ks < 2; ks++) {
        bf16x8 pf = *(const bf16x8*)&lp[w * 1024 +
                                        (cl * 128 + ((ks * 64 + lg * 16) ^ (c7 << 4))) / 2];
#pragma unroll
        for (int nb = 0; nb < 4; nb++) {
          bf16x8 vf = *(const bf16x8*)&lv[cur][((ks * 4 + lg) * 64 + nb * 16 + cl) * 8];
          accO[nb] = mm16(pf, vf, accO[nb]);
        }
      }
      __builtin_amdgcn_s_setprio(0);

      asm volatile("s_waitcnt vmcnt(0)" ::: "memory");
      __builtin_amdgcn_s_barrier();
    }

    float inv[4];
#pragma unroll
    for (int r = 0; r < 4; r++) inv[r] = 1.f / __shfl(lrun, lg * 4 + r);
#pragma unroll
    for (int nb = 0; nb < 4; nb++)
#pragma unroll
      for (int r = 0; r < 4; r++) {
        const int qrow = q0 + w * 16 + lg * 4 + r;
        z_ws[((size_t)b * SEQ + qrow) * D_MODEL + h * 64 + nb * 16 + cl] =
            f2b(accO[nb][r] * inv[r]);
      }
  }
}

// ---------------- launch ----------------
extern "C" void kernel_launch(void* const* d_in, const int* in_sizes, int n_in,
                              void* d_out, int out_size, void* d_ws, size_t ws_size,
                              hipStream_t stream) {
  const float* x = (const float*)d_in[0];
  const float* wq = (const float*)d_in[1];
  const float* bq = (const float*)d_in[2];
  const float* wk = (const float*)d_in[3];
  const float* bk = (const float*)d_in[4];
  const float* wv = (const float*)d_in[5];
  const float* bv = (const float*)d_in[6];
  const float* wo = (const float*)d_in[7];
  const float* bo = (const float*)d_in[8];
  float* out = (float*)d_out;

  char* ws = (char*)d_ws;
  size_t off = 0;
  auto carve = [&](size_t bytes) -> u16* {
    u16* p = (u16*)(ws + off);
    off += (bytes + 255) & ~(size_t)255;
    return p;
  };
  u16* xb = carve((size_t)8192 * 768 * 2);
  u16* wt = carve((size_t)1536 * 768 * 2);
  u16* wvt = carve((size_t)768 * 768 * 2);
  u16* wot = carve((size_t)768 * 768 * 2);
  u16* qw = carve((size_t)BB * NH * SEQ * 64 * 2);
  u16* kw = carve((size_t)BB * NH * SEQ * 64 * 2);
  u16* vw = carve((size_t)BB * NH * SEQ * 64 * 2);
  u16* zw = carve((size_t)8192 * 768 * 2);
  if (ws_size < off) return;

  cast_x_kernel<<<dim3(6144), dim3(256), 0, stream>>>(x, xb);
  pack_w_kernel<<<dim3(4608), dim3(256), 0, stream>>>(wq, wk, wv, wo, wt, wvt, wot);
  gemm_kernel<0><<<dim3(12, 64), dim3(256), 0, stream>>>(
      xb, wt, bq, bk, qw, kw, nullptr);
  gemm_kernel<2><<<dim3(64, 6), dim3(256), 0, stream>>>(
      wvt, xb, bv, nullptr, vw, nullptr, nullptr);
  attn_kernel<<<dim3(16, 48), dim3(256), 0, stream>>>(qw, kw, vw, zw);
  gemm_kernel<1><<<dim3(6, 64), dim3(256), 0, stream>>>(
      zw, wot, bo, nullptr, nullptr, nullptr, out);
}